// Round 13
// baseline (68.863 us; speedup 1.0000x reference)
//
#include <hip/hip_runtime.h>

#define B_TOT 2048
#define NHEAD 3

typedef __attribute__((ext_vector_type(8))) short short8v;
typedef __attribute__((ext_vector_type(4))) float f32x4;
typedef __attribute__((ext_vector_type(2))) __fp16 f16x2;

#define LOG2E 1.4426950408889634f

static __device__ __forceinline__ unsigned short f2bf(float x) {
    unsigned u = __builtin_bit_cast(unsigned, x);
    u += 0x7FFFu + ((u >> 16) & 1u);
    return (unsigned short)(u >> 16);
}
static __device__ __forceinline__ float bf2f(unsigned short s) {
    unsigned u = ((unsigned)s) << 16;
    return __builtin_bit_cast(float, u);
}
static __device__ __forceinline__ float exp2_fast(float x) {
    float r; asm("v_exp_f32 %0, %1" : "=v"(r) : "v"(x)); return r;
}

// ---------------------------------------------------------------------------
// Bias MLP precompute (verified r7-r12), coalesced C-init layout:
//   bias2[((h*16 + mt*4 + nt) * 64 + lane) * 4 + r]
// ---------------------------------------------------------------------------
__global__ __launch_bounds__(256) void bias_kernel(const float* __restrict__ w1,
                                                   const float* __restrict__ b1,
                                                   const float* __restrict__ w2,
                                                   const float* __restrict__ b2,
                                                   float* __restrict__ bias2) {
    int t = blockIdx.x * 256 + threadIdx.x;   // 0..12287
    int h = t >> 12;
    int lane = (t >> 6) & 63;
    int pair = t & 63;
    int g = lane >> 4, c = lane & 15;
    int mt = pair >> 4, nt = (pair >> 2) & 3, r = pair & 3;
    int n = 16 * mt + 4 * g + r;
    int m = 16 * nt + c;

    float d0 = (float)((n >> 3) - (m >> 3));
    float d1 = (float)((n & 7) - (m & 7));
    float r0 = (d0 > 0.f ? 1.f : (d0 < 0.f ? -1.f : 0.f)) * log1pf(fabsf(d0));
    float r1 = (d1 > 0.f ? 1.f : (d1 < 0.f ? -1.f : 0.f)) * log1pf(fabsf(d1));
    float a = 0.f;
    for (int j = 0; j < 256; j++) {
        float hd = fmaf(r0, w1[j], fmaf(r1, w1[256 + j], b1[j]));
        hd = fmaxf(hd, 0.f);
        a = fmaf(hd, w2[j * 3 + h], a);
    }
    bias2[((h * 16 + mt * 4 + nt) * 64 + lane) * 4 + r] = (a + b2[h]) * LOG2E;
}

// ---------------------------------------------------------------------------
// Main kernel = round-12 passing kernel (66.3us) + three changes:
//  (1) per-wave LDS 9216->8192B via XOR swizzle instead of stride padding:
//      q linear [64][32] (row-broadcast reads conflict-free), O swizzled
//      dword col ^ ((row&7)<<2), P [64][64]bf16 swizzled half col ^ ((row&7)<<3).
//      Block LDS 32768 -> 5 blocks/CU (was 4).
//  (2) V-raw global loads hoisted before the post-conv barrier (latency hides
//      under O-frag LDS reads + packing).
//  (3) P-store pack via v_cvt_pk_bf16_f32(e,e) (order-symmetric, 1 instr).
// ---------------------------------------------------------------------------
__global__ __launch_bounds__(256, 3) void attn_kernel(const float* __restrict__ qkv,
                                                      const float* __restrict__ bias2,
                                                      float* __restrict__ out) {
    // per-wave 8192B region: q [64][32] f32 (linear) -> O [64][32] f32 (swz)
    //                        -> P [64][64] bf16 (swz)
    __shared__ float smem[4][64 * 32];

    const int t = threadIdx.x;
    const int w = t >> 6;
    const int lane = t & 63;
    const int h = blockIdx.x % 3;
    const int b = (blockIdx.x / 3) * 4 + w;
    const int g = lane >> 4, c = lane & 15;

    float* Qs = smem[w];
    const float* base = qkv + (size_t)b * (64 * 288) + h * 32;
    const float QS = 0.17677669529663687f * LOG2E;   // 32^-0.5 * log2e

    // ---- q -> LDS (scaled), linear [64][32], coalesced float4 ----
    {
        const int nr = lane >> 3, d0 = (lane & 7) * 4;
        #pragma unroll
        for (int s = 0; s < 8; s++) {
            int n = 8 * s + nr;
            float4 q4 = *(const float4*)(base + n * 288 + d0);
            q4.x *= QS; q4.y *= QS; q4.z *= QS; q4.w *= QS;
            *(float4*)(Qs + n * 32 + d0) = q4;
        }
    }

    // ---- k reversed-pairs (channel dd), rows rotated by 4*H2:
    // krp[t8][i] = {k[i], k[(i-1)&7]} (f16x2) ----
    const int dd = lane & 31, H2 = lane >> 5;
    f16x2 krp[64];
    #pragma unroll
    for (int t8 = 0; t8 < 8; t8++) {
        const int rb = ((t8 + 4 * H2) & 7) * 8;
        float k8[8];
        #pragma unroll
        for (int tx = 0; tx < 8; tx++)
            k8[tx] = base[(rb + tx) * 288 + 96 + dd];
        #pragma unroll
        for (int i = 0; i < 8; i++)
            krp[t8 * 8 + i] = __builtin_amdgcn_cvt_pkrtz(k8[i], k8[(i - 1) & 7]);
    }

    asm volatile("s_waitcnt lgkmcnt(0)" ::: "memory");

    // ---- stage 1: 8x8 cyclic conv via f16 dot2, f32 accumulate ----
    float acc[4][8];
    #pragma unroll
    for (int yi = 0; yi < 4; yi++)
        #pragma unroll
        for (int x = 0; x < 8; x++) acc[yi][x] = 0.f;

    #pragma unroll
    for (int u = 0; u < 8; u++) {
        f16x2 q2[4];
        #pragma unroll
        for (int j = 0; j < 4; j++) {
            float qa = Qs[(u * 8 + 2 * j) * 32 + dd];
            float qb = Qs[(u * 8 + 2 * j + 1) * 32 + dd];
            q2[j] = __builtin_amdgcn_cvt_pkrtz(qa, qb);
        }
        #pragma unroll
        for (int yi = 0; yi < 4; yi++) {
            const int s = (yi - u) & 7;
            #pragma unroll
            for (int x = 0; x < 8; x++) {
                #pragma unroll
                for (int j = 0; j < 4; j++)
                    acc[yi][x] = __builtin_amdgcn_fdot2(
                        q2[j], krp[s * 8 + ((x - 2 * j) & 7)], acc[yi][x], false);
            }
        }
    }

    // ---- O into same LDS region, swizzled: elem (row,d) at row*32 + (d ^ 4*(row&7)).
    // Here row = n + x with n multiple of 8 -> row&7 = x (compile-time). ----
    #pragma unroll
    for (int yi = 0; yi < 4; yi++) {
        const int n = (4 * H2 + yi) * 8;
        #pragma unroll
        for (int x = 0; x < 8; x++)
            Qs[(n + x) * 32 + (dd ^ (4 * x))] = acc[yi][x];
    }

    // ---- V-raw loads hoisted here: latency hides under O-frag reads/packing ----
    float4 vr0[4], vr1[4];
    #pragma unroll
    for (int nt = 0; nt < 4; nt++) {
        const float* vp = base + (16 * nt + c) * 288 + 192 + 8 * g;
        vr0[nt] = *(const float4*)vp;
        vr1[nt] = *(const float4*)(vp + 4);
    }

    asm volatile("s_waitcnt lgkmcnt(0)" ::: "memory");

    // ---- A-frags of O (hi/lo bf16): row = 16*mt + c (row&7 = c&7) ----
    const int sA = (c & 7) << 2;
    short8v Oh[4], Ol[4];
    #pragma unroll
    for (int mt = 0; mt < 4; mt++) {
        const float* rowp = Qs + (16 * mt + c) * 32;
        float4 x0 = *(const float4*)(rowp + ((8 * g) ^ sA));
        float4 x1 = *(const float4*)(rowp + ((8 * g + 4) ^ sA));
        float xs[8] = {x0.x, x0.y, x0.z, x0.w, x1.x, x1.y, x1.z, x1.w};
        #pragma unroll
        for (int j = 0; j < 8; j++) {
            unsigned short hb = f2bf(xs[j]);
            Oh[mt][j] = (short)hb;
            Ol[mt][j] = (short)f2bf(xs[j] - bf2f(hb));
        }
    }

    // ---- B-frags of V^T (hi/lo) from the hoisted registers ----
    short8v Vh[4], Vl[4];
    #pragma unroll
    for (int nt = 0; nt < 4; nt++) {
        float xs[8] = {vr0[nt].x, vr0[nt].y, vr0[nt].z, vr0[nt].w,
                       vr1[nt].x, vr1[nt].y, vr1[nt].z, vr1[nt].w};
        #pragma unroll
        for (int j = 0; j < 8; j++) {
            unsigned short hb = f2bf(xs[j]);
            Vh[nt][j] = (short)hb;
            Vl[nt][j] = (short)f2bf(xs[j] - bf2f(hb));
        }
    }

    // ---- S = O * V^T via MFMA (bias C-init; hh+hl+lh ~= fp32) ----
    const float* bb = bias2 + (size_t)h * 16 * 256 + lane * 4;
    f32x4 S[4][4];
    #pragma unroll
    for (int mt = 0; mt < 4; mt++)
        #pragma unroll
        for (int nt = 0; nt < 4; nt++) {
            f32x4 a = __builtin_bit_cast(f32x4, *(const float4*)(bb + (mt * 4 + nt) * 256));
            a = __builtin_amdgcn_mfma_f32_16x16x32_bf16(Oh[mt], Vh[nt], a, 0, 0, 0);
            a = __builtin_amdgcn_mfma_f32_16x16x32_bf16(Oh[mt], Vl[nt], a, 0, 0, 0);
            a = __builtin_amdgcn_mfma_f32_16x16x32_bf16(Ol[mt], Vh[nt], a, 0, 0, 0);
            S[mt][nt] = a;
        }

    // ---- prefetch V for PV stage (raw f32, consumed after softmax) ----
    float vb[2][2][8];   // [kt][dt][j] = V[32*kt + 8*g + j][16*dt + c]
    #pragma unroll
    for (int kt = 0; kt < 2; kt++)
        #pragma unroll
        for (int dt = 0; dt < 2; dt++)
            #pragma unroll
            for (int j = 0; j < 8; j++)
                vb[kt][dt][j] = base[(32 * kt + 8 * g + j) * 288 + 192 + 16 * dt + c];

    // ---- softmax (max-subtracted, exp2 domain) ----
    float inv[4][4];
    #pragma unroll
    for (int mt = 0; mt < 4; mt++) {
        #pragma unroll
        for (int r = 0; r < 4; r++) {
            float m0 = fmaxf(fmaxf(S[mt][0][r], S[mt][1][r]), fmaxf(S[mt][2][r], S[mt][3][r]));
            m0 = fmaxf(m0, __shfl_xor(m0, 1, 64));
            m0 = fmaxf(m0, __shfl_xor(m0, 2, 64));
            m0 = fmaxf(m0, __shfl_xor(m0, 4, 64));
            m0 = fmaxf(m0, __shfl_xor(m0, 8, 64));
            float s0 = 0.f;
            #pragma unroll
            for (int nt = 0; nt < 4; nt++) {
                float e = exp2_fast(S[mt][nt][r] - m0);
                S[mt][nt][r] = e;
                s0 += e;
            }
            s0 += __shfl_xor(s0, 1, 64);
            s0 += __shfl_xor(s0, 2, 64);
            s0 += __shfl_xor(s0, 4, 64);
            s0 += __shfl_xor(s0, 8, 64);
            inv[mt][r] = 1.f / s0;
        }
    }

    // ---- P (unnormalized) -> LDS bf16 [64][64] swizzled (aliases O region):
    // elem (row,m) at row*64 + (m ^ 8*(row&7)); here row&7 = (4g+r)&7. ----
    unsigned short* Ps = (unsigned short*)Qs;
    #pragma unroll
    for (int mt = 0; mt < 4; mt++)
        #pragma unroll
        for (int r = 0; r < 4; r++) {
            const int prow = 16 * mt + 4 * g + r;
            const int s8 = ((4 * g + r) & 7) << 3;
            #pragma unroll
            for (int nt = 0; nt < 4; nt++) {
                float e = S[mt][nt][r];
                unsigned pe;
                asm("v_cvt_pk_bf16_f32 %0, %1, %2" : "=v"(pe) : "v"(e), "v"(e));
                Ps[prow * 64 + ((16 * nt + c) ^ s8)] = (unsigned short)pe;
            }
        }
    asm volatile("s_waitcnt lgkmcnt(0)" ::: "memory");

    // ---- P A-frags: row = 16*mt + c (row&7 = c&7), k-chunk 32*kt + 8*g ----
    const int s8p = (c & 7) << 3;
    short8v Pf[4][2];
    #pragma unroll
    for (int mt = 0; mt < 4; mt++)
        #pragma unroll
        for (int kt = 0; kt < 2; kt++)
            Pf[mt][kt] = *(const short8v*)(Ps + (16 * mt + c) * 64 + ((32 * kt + 8 * g) ^ s8p));

    // ---- V B-frags for PV (single bf16) ----
    short8v Vp[2][2];
    #pragma unroll
    for (int kt = 0; kt < 2; kt++)
        #pragma unroll
        for (int dt = 0; dt < 2; dt++)
            #pragma unroll
            for (int j = 0; j < 8; j++)
                Vp[kt][dt][j] = (short)f2bf(vb[kt][dt][j]);

    // ---- X = P * V via MFMA ----
    f32x4 X[4][2];
    #pragma unroll
    for (int mt = 0; mt < 4; mt++)
        #pragma unroll
        for (int dt = 0; dt < 2; dt++) {
            f32x4 a = {0.f, 0.f, 0.f, 0.f};
            a = __builtin_amdgcn_mfma_f32_16x16x32_bf16(Pf[mt][0], Vp[0][dt], a, 0, 0, 0);
            a = __builtin_amdgcn_mfma_f32_16x16x32_bf16(Pf[mt][1], Vp[1][dt], a, 0, 0, 0);
            X[mt][dt] = a;
        }

    // ---- normalize + store: out[b][n][h*32 + d] ----
    float* op = out + (size_t)b * (64 * 96) + h * 32;
    #pragma unroll
    for (int mt = 0; mt < 4; mt++)
        #pragma unroll
        for (int dt = 0; dt < 2; dt++)
            #pragma unroll
            for (int r = 0; r < 4; r++)
                op[(16 * mt + 4 * g + r) * 96 + 16 * dt + c] = X[mt][dt][r] * inv[mt][r];
}

extern "C" void kernel_launch(void* const* d_in, const int* in_sizes, int n_in,
                              void* d_out, int out_size, void* d_ws, size_t ws_size,
                              hipStream_t stream) {
    const float* qkv = (const float*)d_in[0];
    const float* w1  = (const float*)d_in[1];
    const float* b1  = (const float*)d_in[2];
    const float* w2  = (const float*)d_in[3];
    const float* b2  = (const float*)d_in[4];
    float* out = (float*)d_out;
    float* bias2 = (float*)d_ws;   // 3*16*64*4 floats = 48 KB

    bias_kernel<<<48, 256, 0, stream>>>(w1, b1, w2, b2, bias2);
    attn_kernel<<<(B_TOT / 4) * NHEAD, 256, 0, stream>>>(qkv, bias2, out);
}